// Round 7
// baseline (226.674 us; speedup 1.0000x reference)
//
#include <hip/hip_runtime.h>

#define IMG_H 512
#define IMG_W 512
#define TILE_H 32
#define ROWS (TILE_H + 10)   // 42 streamed rows per wave-tile

__device__ __forceinline__ int reflect512(int t) {
    t = (t < 0) ? -t : t;
    t = (t > 511) ? 1022 - t : t;
    return t;
}

// 128-thread blocks = 2 independent waves, each owning a 64x32 output tile.
// NO LDS. Each lane loads its own 11 horizontal taps straight from global
// (per-lane reflected byte-offsets, row-invariant, against per-row SCALAR
// bases -> saddr-form global_load_dword). Tap loads are SOFTWARE-PIPELINED
// ONE ROW AHEAD into a double buffer (parity r&1, static under unroll-12),
// so each row's ~130 VALU ops cover the next row's L1 latency in-wave.
// Horizontal 11-tap blur of {a,b,a^2+b^2,ab}; vertical 11-tap blur from a
// 12-deep register ring (slot s%12, static). fp32 -> pure VALU kernel.
// No min-waves bound (R3: (128,6) forced VGPR=40 -> 1.6 GB spill traffic).
__global__ __launch_bounds__(128) void ssim_kernel(
    const float* __restrict__ img1,
    const float* __restrict__ img2,
    float* __restrict__ out)
{
    // gaussian(11, sigma=1.5), L1-normalized (symmetric)
    const float kW[11] = {
        0.00102838f, 0.00759876f, 0.03600078f, 0.10936055f, 0.21300561f,
        0.26601182f, 0.21300561f, 0.10936055f, 0.03600078f, 0.00759876f,
        0.00102838f };
    const float C1 = 0.0001f;  // (0.01*1)^2
    const float C2 = 0.0009f;  // (0.03*1)^2

    const int tid  = threadIdx.x;
    const int wv   = tid >> 6;        // wave id within block (0/1)
    const int lane = tid & 63;
    const int x0 = blockIdx.x * 64;
    // wave-uniform -> SGPR, so per-row bases stay scalar
    const int y0 = __builtin_amdgcn_readfirstlane(blockIdx.y * 64 + wv * TILE_H);
    const size_t pbase = (size_t)blockIdx.z * (IMG_H * IMG_W);
    const float* __restrict__ p1 = img1 + pbase;
    const float* __restrict__ p2 = img2 + pbase;
    float* __restrict__ po = out + pbase;

    // per-lane reflected x byte-offsets for the 11 taps (row-invariant,
    // uniform code path for edge tiles)
    int offB[11];
    #pragma unroll
    for (int k = 0; k < 11; ++k)
        offB[k] = reflect512(x0 - 5 + lane + k) * 4;

    // 12-deep register rings (slot = s % 12, compile-time under unroll-12)
    float ring1[12], ring2[12], ringSS[12], ringAB[12];
    // double-buffered tap registers: row s lives in buffer (s & 1)
    float aT[2][11], bT[2][11];

    const int xo = x0 + lane;

    // ---- prologue: load row 0's taps into buffer 0 ----
    {
        const int gy = reflect512(y0 - 5);
        const char* r1p = (const char*)(p1 + (size_t)gy * IMG_W);
        const char* r2p = (const char*)(p2 + (size_t)gy * IMG_W);
        #pragma unroll
        for (int k = 0; k < 11; ++k) {
            aT[0][k] = *(const float*)(r1p + offB[k]);
            bT[0][k] = *(const float*)(r2p + offB[k]);
        }
    }

    #pragma unroll 1                   // outer loop stays rolled
    for (int so = 0; so < 48; so += 12) {
        #pragma unroll
        for (int r = 0; r < 12; ++r) {
            const int s = so + r;      // so % 12 == 0 -> s % 12 == r, s&1 == r&1
            if (s < ROWS) {
                const int cur = r & 1;         // static
                const int nxt = cur ^ 1;       // static

                // ---- issue row s+1's 22 tap loads (consumed next iter;
                //      this row's ~130 VALU ops hide the L1 latency) ----
                if (s + 1 < ROWS) {
                    const int gy = reflect512(y0 - 5 + s + 1);
                    const char* r1p = (const char*)(p1 + (size_t)gy * IMG_W);
                    const char* r2p = (const char*)(p2 + (size_t)gy * IMG_W);
                    #pragma unroll
                    for (int k = 0; k < 11; ++k) {
                        aT[nxt][k] = *(const float*)(r1p + offB[k]);
                        bT[nxt][k] = *(const float*)(r2p + offB[k]);
                    }
                }

                // ---- horizontal 11-tap blur of {a, b, a^2+b^2, ab} ----
                float h1 = 0.f, h2 = 0.f, hss = 0.f, hab = 0.f;
                #pragma unroll
                for (int k = 0; k < 11; ++k) {
                    const float a = aT[cur][k];
                    const float b = bT[cur][k];
                    const float wk = kW[k];
                    const float ta = wk * a;
                    const float tb = wk * b;
                    h1 += ta;
                    h2 += tb;
                    hss = fmaf(ta, a, hss);
                    hss = fmaf(tb, b, hss);
                    hab = fmaf(ta, b, hab);
                }
                ring1[r] = h1; ring2[r] = h2; ringSS[r] = hss; ringAB[r] = hab;

                // ---- vertical 11-tap blur + SSIM epilogue ----
                if (s >= 10) {
                    float v1 = 0.f, v2 = 0.f, vss = 0.f, vab = 0.f;
                    #pragma unroll
                    for (int d = 0; d < 11; ++d) {
                        const int slot = (r - d + 12) % 12;  // compile-time
                        const float wd = kW[d];              // symmetric
                        v1  = fmaf(wd, ring1[slot],  v1);
                        v2  = fmaf(wd, ring2[slot],  v2);
                        vss = fmaf(wd, ringSS[slot], vss);
                        vab = fmaf(wd, ringAB[slot], vab);
                    }
                    const float mu12 = v1 * v2;
                    const float musq = fmaf(v1, v1, v2 * v2);
                    const float sgsum = vss - musq;          // sig1^2+sig2^2
                    const float sg12  = vab - mu12;          // sigma12
                    const float num = fmaf(2.f, mu12, C1) * fmaf(2.f, sg12, C2);
                    const float den = (musq + C1) * (sgsum + C2);
                    const float rden = __builtin_amdgcn_rcpf(den);  // ~1 ulp
                    const float ssim = num * rden;
                    const float loss = 0.5f * fminf(fmaxf(1.f - ssim, 0.f), 1.f);
                    po[(size_t)(y0 + s - 10) * IMG_W + xo] = loss;
                }
            }
        }
    }
}

extern "C" void kernel_launch(void* const* d_in, const int* in_sizes, int n_in,
                              void* d_out, int out_size, void* d_ws, size_t ws_size,
                              hipStream_t stream) {
    const float* img1 = (const float*)d_in[0];
    const float* img2 = (const float*)d_in[1];
    float* out = (float*)d_out;
    // 8 x 8 x 48 blocks of 128 threads; 2 independent waves/block,
    // each wave one 64x32 tile -> 6144 wave-tiles, 24 waves/CU offered.
    dim3 grid(IMG_W / 64, IMG_H / 64, 48);
    ssim_kernel<<<grid, dim3(128, 1, 1), 0, stream>>>(img1, img2, out);
}

// Round 8
// 176.578 us; speedup vs baseline: 1.2837x; 1.2837x over previous
//
#include <hip/hip_runtime.h>

#define IMG_H 512
#define IMG_W 512
#define TILE_H 32
#define ROWS (TILE_H + 10)      // 42 staged rows per wave-tile
#define NSLOT 8                 // LDS row-ring depth = prefetch distance
#define SLOT_F 256              // floats per slot: 2 images x 128

__device__ __forceinline__ int reflect512(int t) {
    t = (t < 0) ? -t : t;
    t = (t > 511) ? 1022 - t : t;
    return t;
}

// fire-and-forget global->LDS DMA (dword per lane). No VGPR destination
// => compiler emits no automatic vmcnt waits => counted-vmcnt pipeline
// survives at HIP source level (the m97/T4 property). Global src is
// PER-LANE (reflected); LDS dest is wave-uniform base + lane*4.
__device__ __forceinline__ void gload_lds(const void* g, void* l) {
    __builtin_amdgcn_global_load_lds(
        (const __attribute__((address_space(1))) void*)g,
        (__attribute__((address_space(3))) void*)l, 4, 0, 0);
}

// 128-thread blocks = 2 independent waves (own LDS half, own 64x32 tile,
// ZERO barriers). Per wave: 8-row LDS ring staged by global_load_lds,
// ~28-32 loads (~60 HBM lines) in flight at all times -> fixes the
// MLP-starvation that capped R1-R7 at ~1.2 TB/s effective HBM BW.
// Per row: s_waitcnt vmcnt(28) [7 younger rows x 4 issues; VMEM retires
// in order, so interleaved stores only make the wait stronger], then
// horizontal 11-tap blur of {a,b,a^2+b^2,ab} from LDS (stride-1 ds_read,
// 2 lanes/bank = conflict-free), vertical 11-tap blur from a 12-deep
// register ring (static indices under unroll-12), fused SSIM epilogue,
// then re-stage the freed slot. fp32 -> pure VALU + DMA kernel.
__global__ __launch_bounds__(128) void ssim_kernel(
    const float* __restrict__ img1,
    const float* __restrict__ img2,
    float* __restrict__ out)
{
    // gaussian(11, sigma=1.5), L1-normalized (symmetric)
    const float kW[11] = {
        0.00102838f, 0.00759876f, 0.03600078f, 0.10936055f, 0.21300561f,
        0.26601182f, 0.21300561f, 0.10936055f, 0.03600078f, 0.00759876f,
        0.00102838f };
    const float C1 = 0.0001f;  // (0.01*1)^2
    const float C2 = 0.0009f;  // (0.03*1)^2

    const int tid  = threadIdx.x;
    const int wv   = tid >> 6;
    const int lane = tid & 63;
    const int x0 = blockIdx.x * 64;
    const int y0 = __builtin_amdgcn_readfirstlane(blockIdx.y * 64 + wv * TILE_H);
    const size_t pbase = (size_t)blockIdx.z * (IMG_H * IMG_W);
    const float* __restrict__ p1 = img1 + pbase;
    const float* __restrict__ p2 = img2 + pbase;
    float* __restrict__ po = out + pbase;

    __shared__ float ring[2][NSLOT * SLOT_F];   // 16 KB / block
    float* const myring = ring[wv];

    // per-lane reflected global byte offsets (row-invariant; edges folded in)
    const int oMain = reflect512(x0 - 5 + lane) * 4;   // LDS idx lane   (px x0-5+lane)
    const int oTail = reflect512(x0 + 59 + lane) * 4;  // LDS idx 64+lane (px x0+59+lane; lanes>=10 garbage, unread)

    // 12-deep register rings (slot = s % 12, compile-time under unroll-12)
    float r1q[12], r2q[12], rsq[12], rab[12];
    const int xo = x0 + lane;

    // ---- prologue: stage rows 0..7 into slots 0..7 (32 DMA issues) ----
    #pragma unroll
    for (int p = 0; p < NSLOT; ++p) {
        const int gy = reflect512(y0 - 5 + p);
        const char* a = (const char*)p1 + gy * (IMG_W * 4);
        const char* b = (const char*)p2 + gy * (IMG_W * 4);
        float* ls = myring + p * SLOT_F;
        gload_lds(a + oMain, ls);
        gload_lds(a + oTail, ls + 64);
        gload_lds(b + oMain, ls + 128);
        gload_lds(b + oTail, ls + 192);
    }

    #pragma unroll 1                   // outer loop stays rolled
    for (int so = 0; so < 48; so += 12) {
        #pragma unroll
        for (int r = 0; r < 12; ++r) {
            const int s = so + r;      // s % 12 == r (static)
            if (s < ROWS) {
                // row s's 4 loads are the oldest beyond the 28 younger
                // (rows s+1..s+7); in-order VMEM retirement => they're done.
                asm volatile("s_waitcnt vmcnt(28)" ::: "memory");

                const float* sp = myring + (s & 7) * SLOT_F + lane;

                // ---- horizontal 11-tap blur of {a, b, a^2+b^2, ab} ----
                float h1 = 0.f, h2 = 0.f, hss = 0.f, hab = 0.f;
                #pragma unroll
                for (int k = 0; k < 11; ++k) {
                    const float a = sp[k];          // img1 taps
                    const float b = sp[128 + k];    // img2 taps
                    const float wk = kW[k];
                    const float ta = wk * a;
                    const float tb = wk * b;
                    h1 += ta;
                    h2 += tb;
                    hss = fmaf(ta, a, hss);
                    hss = fmaf(tb, b, hss);
                    hab = fmaf(ta, b, hab);
                }
                r1q[r] = h1; r2q[r] = h2; rsq[r] = hss; rab[r] = hab;

                // ---- vertical 11-tap blur + SSIM epilogue ----
                if (s >= 10) {
                    float v1 = 0.f, v2 = 0.f, vss = 0.f, vab = 0.f;
                    #pragma unroll
                    for (int d = 0; d < 11; ++d) {
                        const int slot = (r - d + 12) % 12;  // compile-time
                        const float wd = kW[d];              // symmetric
                        v1  = fmaf(wd, r1q[slot], v1);
                        v2  = fmaf(wd, r2q[slot], v2);
                        vss = fmaf(wd, rsq[slot], vss);
                        vab = fmaf(wd, rab[slot], vab);
                    }
                    const float mu12 = v1 * v2;
                    const float musq = fmaf(v1, v1, v2 * v2);
                    const float sgsum = vss - musq;          // sig1^2+sig2^2
                    const float sg12  = vab - mu12;          // sigma12
                    const float num = fmaf(2.f, mu12, C1) * fmaf(2.f, sg12, C2);
                    const float den = (musq + C1) * (sgsum + C2);
                    const float rden = __builtin_amdgcn_rcpf(den);  // ~1 ulp
                    const float ssim = num * rden;
                    const float loss = 0.5f * fminf(fmaxf(1.f - ssim, 0.f), 1.f);
                    po[(size_t)(y0 + s - 10) * IMG_W + xo] = loss;
                }

                // ---- re-stage freed slot with row s+8 (clamped) ----
                // sched_barrier pins the DMA issue below the ds_reads of
                // the same slot (WAR on LDS the aliaser can't prove).
                __builtin_amdgcn_sched_barrier(0);
                {
                    const int srow = (s + 8 > ROWS - 1) ? ROWS - 1 : s + 8;
                    const int gy = reflect512(y0 - 5 + srow);
                    const char* a = (const char*)p1 + gy * (IMG_W * 4);
                    const char* b = (const char*)p2 + gy * (IMG_W * 4);
                    float* ls = myring + ((s + 8) & 7) * SLOT_F;
                    gload_lds(a + oMain, ls);
                    gload_lds(a + oTail, ls + 64);
                    gload_lds(b + oMain, ls + 128);
                    gload_lds(b + oTail, ls + 192);
                }
            }
        }
    }
    // drain DMA before LDS dealloc/reuse by the next block
    asm volatile("s_waitcnt vmcnt(0) lgkmcnt(0)" ::: "memory");
}

extern "C" void kernel_launch(void* const* d_in, const int* in_sizes, int n_in,
                              void* d_out, int out_size, void* d_ws, size_t ws_size,
                              hipStream_t stream) {
    const float* img1 = (const float*)d_in[0];
    const float* img2 = (const float*)d_in[1];
    float* out = (float*)d_out;
    // 8 x 8 x 48 blocks of 128 threads; 2 independent waves/block,
    // each wave one 64x32 tile -> 6144 wave-tiles; LDS (16KB) caps
    // residency at 10 blocks = 20 waves/CU.
    dim3 grid(IMG_W / 64, IMG_H / 64, 48);
    ssim_kernel<<<grid, dim3(128, 1, 1), 0, stream>>>(img1, img2, out);
}